// Round 16
// baseline (224.443 us; speedup 1.0000x reference)
//
#include <hip/hip_runtime.h>

#define LORA_RANK 16
#define SCALING 2.0f

using bf16x8 = __attribute__((ext_vector_type(8))) __bf16;
using f32x4  = __attribute__((ext_vector_type(4))) float;
using i32x4  = __attribute__((ext_vector_type(4))) int;

#define GLB(p) ((const __attribute__((address_space(1))) void*)(p))
#define LDS(p) ((__attribute__((address_space(3))) void*)(p))

// ---------------------------------------------------------------------------
// Fused prep: blocks [0,N) -> quantize W row o (LoRA computed on the fly,
// lA served from L2); blocks [N,N+M) -> quantize X row m.
// One launch replaces lora_mat + quant_w + quant_x (kills L round-trip and
// two dispatch gaps).
// ---------------------------------------------------------------------------
__global__ __launch_bounds__(256) void fused_quant_kernel(
    const float* __restrict__ X, const int* __restrict__ q,
    const float* __restrict__ scales,
    const float* __restrict__ lA, const float* __restrict__ lB,
    signed char* __restrict__ W8, signed char* __restrict__ X8,
    float* __restrict__ sn, float* __restrict__ sxm, int N, int K)
{
    const int b = blockIdx.x, t = threadIdx.x;
    const int lane = t & 63, wid = t >> 6;
    __shared__ float wm[4];

    if (b < N) {
        // ---- W path: row o = b ----
        const int o = b;
        const float s = scales[o];
        float bb[LORA_RANK];
        #pragma unroll
        for (int r = 0; r < LORA_RANK; ++r)
            bb[r] = lB[(long)o * LORA_RANK + r] * SCALING;   // broadcast loads

        const int4* qr = (const int4*)(q + (long)o * K);
        float w[16];
        float mx = 0.f;
        #pragma unroll
        for (int j = 0; j < 4; ++j) {
            const int c = t + j * 256;                       // int4 index
            int4 qv = qr[c];
            f32x4 l = {0.f, 0.f, 0.f, 0.f};
            #pragma unroll
            for (int r = 0; r < LORA_RANK; ++r) {
                f32x4 av = *(const f32x4*)(lA + (long)r * K + 4 * c);
                l[0] += bb[r] * av[0];
                l[1] += bb[r] * av[1];
                l[2] += bb[r] * av[2];
                l[3] += bb[r] * av[3];
            }
            w[4 * j + 0] = (float)qv.x * s + l[0];
            w[4 * j + 1] = (float)qv.y * s + l[1];
            w[4 * j + 2] = (float)qv.z * s + l[2];
            w[4 * j + 3] = (float)qv.w * s + l[3];
            mx = fmaxf(mx, fmaxf(fmaxf(fabsf(w[4 * j]), fabsf(w[4 * j + 1])),
                                 fmaxf(fabsf(w[4 * j + 2]), fabsf(w[4 * j + 3]))));
        }
        #pragma unroll
        for (int off = 32; off; off >>= 1) mx = fmaxf(mx, __shfl_xor(mx, off));
        if (lane == 0) wm[wid] = mx;
        __syncthreads();
        const float gmax = fmaxf(fmaxf(fmaxf(wm[0], wm[1]), fmaxf(wm[2], wm[3])), 1e-30f);
        const float winv = 127.0f / gmax;

        int* wrow = (int*)(W8 + (long)o * K);
        #pragma unroll
        for (int j = 0; j < 4; ++j) {
            int c0 = (int)rintf(fminf(fmaxf(w[4 * j + 0] * winv, -127.f), 127.f));
            int c1 = (int)rintf(fminf(fmaxf(w[4 * j + 1] * winv, -127.f), 127.f));
            int c2 = (int)rintf(fminf(fmaxf(w[4 * j + 2] * winv, -127.f), 127.f));
            int c3 = (int)rintf(fminf(fmaxf(w[4 * j + 3] * winv, -127.f), 127.f));
            wrow[t + j * 256] = (c0 & 255) | ((c1 & 255) << 8) | ((c2 & 255) << 16) | (c3 << 24);
        }
        if (t == 0) sn[o] = gmax / 127.0f;
    } else {
        // ---- X path: row m = b - N ----
        const int m = b - N;
        const f32x4* xr = (const f32x4*)(X + (long)m * K);
        f32x4 v[4];
        float mx = 0.f;
        #pragma unroll
        for (int j = 0; j < 4; ++j) {
            v[j] = xr[t + j * 256];
            mx = fmaxf(mx, fmaxf(fmaxf(fabsf(v[j][0]), fabsf(v[j][1])),
                                 fmaxf(fabsf(v[j][2]), fabsf(v[j][3]))));
        }
        #pragma unroll
        for (int off = 32; off; off >>= 1) mx = fmaxf(mx, __shfl_xor(mx, off));
        if (lane == 0) wm[wid] = mx;
        __syncthreads();
        const float gmax = fmaxf(fmaxf(fmaxf(wm[0], wm[1]), fmaxf(wm[2], wm[3])), 1e-30f);
        const float xinv = 127.0f / gmax;

        int* xrow = (int*)(X8 + (long)m * K);
        #pragma unroll
        for (int j = 0; j < 4; ++j) {
            int c0 = (int)rintf(fminf(fmaxf(v[j][0] * xinv, -127.f), 127.f));
            int c1 = (int)rintf(fminf(fmaxf(v[j][1] * xinv, -127.f), 127.f));
            int c2 = (int)rintf(fminf(fmaxf(v[j][2] * xinv, -127.f), 127.f));
            int c3 = (int)rintf(fminf(fmaxf(v[j][3] * xinv, -127.f), 127.f));
            xrow[t + j * 256] = (c0 & 255) | ((c1 & 255) << 8) | ((c2 & 255) << 16) | (c3 << 24);
        }
        if (t == 0) sxm[m] = gmax / 127.0f;
    }
}

// ---------------------------------------------------------------------------
// INT8 GEMM (champion, 134 us): 256x256 tile, BK=128, 128B rows + 8-chunk
// XOR swizzle (verified conflict-free), flat tile body with SGB interleave
// hint, 1 barrier + 1 vmcnt per K-tile, dbuf 128KB.
// out = acc_i32 * sx[row]*s'[col] + bias[col].
// ---------------------------------------------------------------------------
#define VMW0  asm volatile("s_waitcnt vmcnt(0)" ::: "memory")
#define SB0   __builtin_amdgcn_sched_barrier(0)
#define SGB(mask, n) __builtin_amdgcn_sched_group_barrier((mask), (n), 0)

#define RD4(base, off) (*(const i32x4*)((base) + (off)))

#define MFI(mi, nj, A, B) \
    acc[mi][nj] = __builtin_amdgcn_mfma_i32_16x16x64_i8(A, B, acc[mi][nj], 0, 0, 0)

// stage one 256x128B operand (32KB) = 4 rounds of 8KB (512 thr x 16B)
#define STAGE_I8(dA, dB) do { \
    __builtin_amdgcn_global_load_lds(GLB(pB),          LDS((dB) + wb),         16, 0, 0); \
    __builtin_amdgcn_global_load_lds(GLB(pB + rk),     LDS((dB) + wb +  8192), 16, 0, 0); \
    __builtin_amdgcn_global_load_lds(GLB(pB + 2 * rk), LDS((dB) + wb + 16384), 16, 0, 0); \
    __builtin_amdgcn_global_load_lds(GLB(pB + 3 * rk), LDS((dB) + wb + 24576), 16, 0, 0); \
    __builtin_amdgcn_global_load_lds(GLB(pA),          LDS((dA) + wb),         16, 0, 0); \
    __builtin_amdgcn_global_load_lds(GLB(pA + rk),     LDS((dA) + wb +  8192), 16, 0, 0); \
    __builtin_amdgcn_global_load_lds(GLB(pA + 2 * rk), LDS((dA) + wb + 16384), 16, 0, 0); \
    __builtin_amdgcn_global_load_lds(GLB(pA + 3 * rk), LDS((dA) + wb + 24576), 16, 0, 0); } while (0)

#define ADVP8(a) do { pA += (a); pB += (a); } while (0)

// One K-tile (BK=128 = 2 k-slices of 64), no internal barriers.
#define TILE_I8(Ac, Bc, DOSTAGE) do { \
    const char* _ac = (Ac); const char* _bc = (Bc); \
    DOSTAGE; \
    __builtin_amdgcn_s_setprio(1); \
    { /* k-slice 0 */ \
      i32x4 b0 = RD4(_bc, bRow +    0 + kc0); \
      i32x4 b1 = RD4(_bc, bRow + 2048 + kc0); \
      i32x4 b2 = RD4(_bc, bRow + 4096 + kc0); \
      i32x4 b3 = RD4(_bc, bRow + 6144 + kc0); \
      i32x4 a0 = RD4(_ac, aRow +     0 + kc0); \
      i32x4 a1 = RD4(_ac, aRow +  2048 + kc0); \
      i32x4 a2 = RD4(_ac, aRow +  4096 + kc0); \
      i32x4 a3 = RD4(_ac, aRow +  6144 + kc0); \
      i32x4 a4 = RD4(_ac, aRow +  8192 + kc0); \
      i32x4 a5 = RD4(_ac, aRow + 10240 + kc0); \
      i32x4 a6 = RD4(_ac, aRow + 12288 + kc0); \
      i32x4 a7 = RD4(_ac, aRow + 14336 + kc0); \
      MFI(0,0,a0,b0); MFI(1,0,a1,b0); MFI(2,0,a2,b0); MFI(3,0,a3,b0); \
      MFI(4,0,a4,b0); MFI(5,0,a5,b0); MFI(6,0,a6,b0); MFI(7,0,a7,b0); \
      MFI(0,1,a0,b1); MFI(1,1,a1,b1); MFI(2,1,a2,b1); MFI(3,1,a3,b1); \
      MFI(4,1,a4,b1); MFI(5,1,a5,b1); MFI(6,1,a6,b1); MFI(7,1,a7,b1); \
      MFI(0,2,a0,b2); MFI(1,2,a1,b2); MFI(2,2,a2,b2); MFI(3,2,a3,b2); \
      MFI(4,2,a4,b2); MFI(5,2,a5,b2); MFI(6,2,a6,b2); MFI(7,2,a7,b2); \
      MFI(0,3,a0,b3); MFI(1,3,a1,b3); MFI(2,3,a2,b3); MFI(3,3,a3,b3); \
      MFI(4,3,a4,b3); MFI(5,3,a5,b3); MFI(6,3,a6,b3); MFI(7,3,a7,b3); \
    } \
    { /* k-slice 1 */ \
      i32x4 b0 = RD4(_bc, bRow +    0 + kc1); \
      i32x4 b1 = RD4(_bc, bRow + 2048 + kc1); \
      i32x4 b2 = RD4(_bc, bRow + 4096 + kc1); \
      i32x4 b3 = RD4(_bc, bRow + 6144 + kc1); \
      i32x4 a0 = RD4(_ac, aRow +     0 + kc1); \
      i32x4 a1 = RD4(_ac, aRow +  2048 + kc1); \
      i32x4 a2 = RD4(_ac, aRow +  4096 + kc1); \
      i32x4 a3 = RD4(_ac, aRow +  6144 + kc1); \
      i32x4 a4 = RD4(_ac, aRow +  8192 + kc1); \
      i32x4 a5 = RD4(_ac, aRow + 10240 + kc1); \
      i32x4 a6 = RD4(_ac, aRow + 12288 + kc1); \
      i32x4 a7 = RD4(_ac, aRow + 14336 + kc1); \
      MFI(0,0,a0,b0); MFI(1,0,a1,b0); MFI(2,0,a2,b0); MFI(3,0,a3,b0); \
      MFI(4,0,a4,b0); MFI(5,0,a5,b0); MFI(6,0,a6,b0); MFI(7,0,a7,b0); \
      MFI(0,1,a0,b1); MFI(1,1,a1,b1); MFI(2,1,a2,b1); MFI(3,1,a3,b1); \
      MFI(4,1,a4,b1); MFI(5,1,a5,b1); MFI(6,1,a6,b1); MFI(7,1,a7,b1); \
      MFI(0,2,a0,b2); MFI(1,2,a1,b2); MFI(2,2,a2,b2); MFI(3,2,a3,b2); \
      MFI(4,2,a4,b2); MFI(5,2,a5,b2); MFI(6,2,a6,b2); MFI(7,2,a7,b2); \
      MFI(0,3,a0,b3); MFI(1,3,a1,b3); MFI(2,3,a2,b3); MFI(3,3,a3,b3); \
      MFI(4,3,a4,b3); MFI(5,3,a5,b3); MFI(6,3,a6,b3); MFI(7,3,a7,b3); \
    } \
    SGB(0x30, 8); \
    SGB(0x100, 12); \
    SGB(0x8, 8); SGB(0x100, 3); \
    SGB(0x8, 8); SGB(0x100, 3); \
    SGB(0x8, 8); SGB(0x100, 3); \
    SGB(0x8, 8); SGB(0x100, 3); \
    SGB(0x8, 32); \
    __builtin_amdgcn_s_setprio(0); \
    VMW0; \
    __builtin_amdgcn_s_barrier(); \
    SB0; \
  } while (0)

__global__ __launch_bounds__(512, 2) void gemm_i8_kernel(
    const signed char* __restrict__ X8, const signed char* __restrict__ W8,
    const float* __restrict__ sxm, const float* __restrict__ sn,
    const float* __restrict__ bias, float* __restrict__ C,
    int M, int N, int K)
{
    // buf0 A [0,32K) B [32K,64K) | buf1 A [64K,96K) B [96K,128K)
    __shared__ __align__(16) char smem[131072];

    const int t = threadIdx.x, wid = t >> 6, lane = t & 63;
    const int wr = wid >> 2, wc = wid & 3;
    const int l15 = lane & 15, l7 = lane & 7, lk = lane >> 4;

    const int nwg = gridDim.x;
    int bid = blockIdx.x;
    if ((nwg & 7) == 0) bid = (bid & 7) * (nwg >> 3) + (bid >> 3);
    const int ntn = N >> 8;
    const int m0 = (bid / ntn) << 8, n0 = (bid % ntn) << 8;

    // staging: thread t sources row (t>>3)+64k, chunk (t&7)^((t>>3)&7)
    const int sr = t >> 3;
    const int ch = (t & 7) ^ (sr & 7);
    const long rk = 64L * K;                       // 64-row stride in bytes
    const signed char* pA = X8 + (long)(m0 + sr) * K + ch * 16;
    const signed char* pB = W8 + (long)(n0 + sr) * K + ch * 16;

    const int wb = wid * 1024;                     // wave-uniform stage base

    // fragment reads: row base+l15 (+16*mi), k-chunk (lk + 4*ks) ^ (row&7)
    const int aRow = (wr * 128 + l15) * 128;
    const int bRow = (wc * 64  + l15) * 128;
    const int kc0  = ((lk    ) ^ l7) << 4;
    const int kc1  = ((lk + 4) ^ l7) << 4;

    char* const bA0 = smem;
    char* const bB0 = smem + 32768;
    char* const bA1 = smem + 65536;
    char* const bB1 = smem + 98304;

    i32x4 acc[8][4] = {};

    const int nkt = K >> 7;                        // BK = 128

    STAGE_I8(bA0, bB0);
    ADVP8(nkt > 1 ? 128 : 0);
    VMW0;
    __builtin_amdgcn_s_barrier();
    SB0;

    for (int kt = 0; kt < nkt; kt += 2) {
        const long adv1 = (kt + 2 < nkt) ? 128 : 0;
        const long adv2 = (kt + 3 < nkt) ? 128 : 0;
        TILE_I8(bA0, bB0, { STAGE_I8(bA1, bB1); ADVP8(adv1); });
        TILE_I8(bA1, bB1, { STAGE_I8(bA0, bB0); ADVP8(adv2); });
    }

    // epilogue: col = lane&15 (+nj*16), row = (lane>>4)*4 + e (+mi*16)
    #pragma unroll
    for (int nj = 0; nj < 4; ++nj) {
        const int col = n0 + wc * 64 + nj * 16 + l15;
        const float scol = sn[col];
        const float bv   = bias[col];
        #pragma unroll
        for (int mi = 0; mi < 8; ++mi) {
            const long rowb = (long)m0 + wr * 128 + mi * 16 + (lane >> 4) * 4;
            const f32x4 sx4 = *(const f32x4*)(sxm + rowb);
            float* Cp = C + rowb * N + col;
            Cp[0]       = (float)acc[mi][nj][0] * (sx4[0] * scol) + bv;
            Cp[(long)N] = (float)acc[mi][nj][1] * (sx4[1] * scol) + bv;
            Cp[2L * N]  = (float)acc[mi][nj][2] * (sx4[2] * scol) + bv;
            Cp[3L * N]  = (float)acc[mi][nj][3] * (sx4[3] * scol) + bv;
        }
    }
}

// ---------------------------------------------------------------------------
// Last-resort fallback: on-the-fly dequant+LoRA fp32 GEMM (odd shapes / no ws).
// ---------------------------------------------------------------------------
__global__ __launch_bounds__(256) void fallback_gemm(
    const float* __restrict__ X, const int* __restrict__ q,
    const float* __restrict__ scales, const float* __restrict__ bias,
    const float* __restrict__ lA, const float* __restrict__ lB,
    float* __restrict__ C, int M, int N, int K)
{
    __shared__ float Xs[64][17];
    __shared__ float Ws[64][17];
    __shared__ float At[LORA_RANK][16];
    __shared__ float Bt[64][LORA_RANK];

    const int ntn = N >> 6;
    const int m0 = (blockIdx.x / ntn) << 6, n0 = (blockIdx.x % ntn) << 6;
    const int t = threadIdx.x;

    for (int j = t; j < 64 * LORA_RANK; j += 256)
        Bt[j >> 4][j & 15] = lB[(long)(n0 + (j >> 4)) * LORA_RANK + (j & 15)] * SCALING;

    const int tr = (t & 15) * 4, tc = (t >> 4) * 4;
    float acc[4][4] = {};

    for (int k0 = 0; k0 < K; k0 += 16) {
        __syncthreads();
        for (int j = t; j < 1024; j += 256)
            Xs[j >> 4][j & 15] = X[(long)(m0 + (j >> 4)) * K + k0 + (j & 15)];
        At[t >> 4][t & 15] = lA[(long)(t >> 4) * K + k0 + (t & 15)];
        __syncthreads();
        for (int j = t; j < 1024; j += 256) {
            int o = j >> 4, kk = j & 15;
            float v = (float)q[(long)(n0 + o) * K + k0 + kk] * scales[n0 + o];
            #pragma unroll
            for (int r = 0; r < LORA_RANK; ++r) v += Bt[o][r] * At[r][kk];
            Ws[o][kk] = v;
        }
        __syncthreads();
        #pragma unroll 4
        for (int kk = 0; kk < 16; ++kk)
            #pragma unroll
            for (int i = 0; i < 4; ++i)
                #pragma unroll
                for (int j = 0; j < 4; ++j)
                    acc[i][j] += Xs[tr + i][kk] * Ws[tc + j][kk];
    }
    __syncthreads();
    #pragma unroll
    for (int i = 0; i < 4; ++i)
        #pragma unroll
        for (int j = 0; j < 4; ++j)
            C[(long)(m0 + tr + i) * N + n0 + tc + j] = acc[i][j] + bias[n0 + tc + j];
}

// ---------------------------------------------------------------------------
extern "C" void kernel_launch(void* const* d_in, const int* in_sizes, int n_in,
                              void* d_out, int out_size, void* d_ws, size_t ws_size,
                              hipStream_t stream)
{
    const float* x      = (const float*)d_in[0];
    const int*   qw     = (const int*)d_in[1];
    const float* scales = (const float*)d_in[2];
    const float* bias   = (const float*)d_in[3];
    const float* lA     = (const float*)d_in[4];
    const float* lB     = (const float*)d_in[5];
    float*       out    = (float*)d_out;

    const int K = in_sizes[4] / LORA_RANK;   // 4096
    const int N = in_sizes[2];               // 4096
    const int M = in_sizes[0] / K;           // 8192

    const size_t i8need = (size_t)N * K + (size_t)M * K + (size_t)(M + N) * 4 + 256;
    const bool i8_ok = (K == 4096) && (M % 256) == 0 && (N % 256) == 0 &&
                       ws_size >= i8need;

    if (i8_ok) {
        signed char* W8  = (signed char*)d_ws;
        signed char* X8  = W8 + (size_t)N * K;
        float*       sxm = (float*)(X8 + (size_t)M * K);
        float*       sn  = sxm + M;

        fused_quant_kernel<<<N + M, 256, 0, stream>>>(
            x, qw, scales, lA, lB, W8, X8, sn, sxm, N, K);
        const int nwg = (M / 256) * (N / 256);
        gemm_i8_kernel<<<nwg, 512, 0, stream>>>(X8, W8, sxm, sn, bias, out, M, N, K);
    } else {
        fallback_gemm<<<(M / 64) * (N / 64), 256, 0, stream>>>(
            x, qw, scales, bias, lA, lB, out, M, N, K);
    }
}